// Round 5
// baseline (12994.934 us; speedup 1.0000x reference)
//
#include <hip/hip_runtime.h>
#include <math.h>

#define G_    1024
#define NPG   126
#define EPG   450
#define NN    (G_*NPG)      // 129024
#define EE    (G_*EPG)      // 460800
#define F_    126
#define EPSV  1e-5f
#define NCHUNK 8
#define CH    (NN/NCHUNK)   // 16128 nodes = 128 graphs per chunk

// ---------------- node embedding: h = x @ emb1_w + emb1_b ----------------
__global__ void k_embed(const float* __restrict__ x, const float* __restrict__ w,
                        const float* __restrict__ b, float* __restrict__ h) {
    int idx = blockIdx.x * blockDim.x + threadIdx.x;
    if (idx >= NN * F_) return;
    int n = idx / F_;
    int f = idx - n * F_;
    float v = b[f];
#pragma unroll
    for (int c = 0; c < 5; ++c) v += x[n * 5 + c] * w[c * F_ + f];
    h[idx] = v;
}

// ---------------- per-graph CSR build (one block per graph) ----------------
__global__ void k_build_csr(const int* __restrict__ src, const int* __restrict__ dst,
                            const int* __restrict__ attr,
                            int* __restrict__ deg, int* __restrict__ rstart,
                            int* __restrict__ epack) {
    int g = blockIdx.x;
    __shared__ int scnt[NPG];
    __shared__ int spos[NPG];
    int t = threadIdx.x;
    for (int j = t; j < NPG; j += blockDim.x) scnt[j] = 0;
    __syncthreads();
    int e0 = g * EPG;
    for (int i = t; i < EPG; i += blockDim.x) {
        int dl = dst[e0 + i] - g * NPG;
        atomicAdd(&scnt[dl], 1);
    }
    __syncthreads();
    if (t == 0) {
        int run = 0;
        for (int j = 0; j < NPG; ++j) { spos[j] = run; run += scnt[j]; }
    }
    __syncthreads();
    for (int j = t; j < NPG; j += blockDim.x) {
        deg[g * NPG + j]    = scnt[j];
        rstart[g * NPG + j] = e0 + spos[j];
    }
    __syncthreads();
    for (int j = t; j < NPG; j += blockDim.x) scnt[j] = 0;
    __syncthreads();
    for (int i = t; i < EPG; i += blockDim.x) {
        int e  = e0 + i;
        int dl = dst[e] - g * NPG;
        int p  = atomicAdd(&scnt[dl], 1);
        epack[e0 + spos[dl] + p] = src[e] | (attr[e] << 20);  // src < 2^17, attr < 10
    }
}

// ---------------- per-node degree scalers ----------------
__global__ void k_node_scalars(const int* __restrict__ deg, const int* __restrict__ deg_hist,
                               float* __restrict__ invc, float* __restrict__ ampv,
                               float* __restrict__ attv) {
    int n = blockIdx.x * blockDim.x + threadIdx.x;
    if (n >= NN) return;
    float sum = 0.f, sl = 0.f;
#pragma unroll
    for (int b = 0; b < 5; ++b) {
        float dh = (float)deg_hist[b];
        sum += dh;
        sl  += dh * logf((float)b + 1.f);
    }
    float avg_log = sl / sum;
    float c  = (float)deg[n];
    float cm = fmaxf(c, 1.f);
    invc[n] = 1.f / cm;
    float la = logf(cm + 1.f);
    ampv[n] = la / avg_log;
    attv[n] = avg_log / la;
}

// ---------------- edge-attr table: etab[l][a] = (edge_tab[a]@enc_w+enc_b)@We + pre_b ----------
__global__ void k_build_etab(const float* __restrict__ edge_tab, const float* __restrict__ enc_w,
                             const float* __restrict__ enc_b, const float* __restrict__ pre_w,
                             const float* __restrict__ pre_b, float* __restrict__ etab) {
    int l = blockIdx.x / 10, a = blockIdx.x % 10;
    __shared__ float tmp[F_];
    int t = threadIdx.x;
    if (t < F_) {
        float s = enc_b[l * F_ + t];
        for (int c = 0; c < 50; ++c) s += edge_tab[a * 50 + c] * enc_w[(l * 50 + c) * F_ + t];
        tmp[t] = s;
    }
    __syncthreads();
    if (t < F_) {
        float s = pre_b[l * F_ + t];
        for (int j = 0; j < F_; ++j) s += tmp[j] * pre_w[((size_t)l * 378 + 252 + j) * F_ + t];
        etab[(l * 10 + a) * F_ + t] = s;
    }
}

// ---------------- plain fp32 tiled GEMM: C[M,126] = A[M,K]@B[K,126] (+bias) ----------
__global__ __launch_bounds__(256) void k_gemm_plain(const float* __restrict__ A,
                                                    const float* __restrict__ B,
                                                    float* __restrict__ C, int M, int K,
                                                    const float* __restrict__ bias) {
    __shared__ float As[16][68];
    __shared__ float Bs[16][64];
    int tid = threadIdx.x;
    int m0 = blockIdx.y * 64;
    int n0 = blockIdx.x * 64;
    int tr = tid >> 4, tc = tid & 15;
    int ar = tid >> 4, ak = tid & 15;
    int br = tid >> 6, bn = tid & 63;
    float acc[4][4] = {};
    for (int k0 = 0; k0 < K; k0 += 16) {
#pragma unroll
        for (int i = 0; i < 4; ++i) {
            int row = m0 + ar + 16 * i;
            float v = 0.f;
            if (k0 + ak < K) v = A[(size_t)row * K + k0 + ak];
            As[ak][ar + 16 * i] = v;
        }
#pragma unroll
        for (int i = 0; i < 4; ++i) {
            int kk = k0 + br + 4 * i;
            float v = 0.f;
            if (kk < K && n0 + bn < F_) v = B[(size_t)kk * F_ + n0 + bn];
            Bs[br + 4 * i][bn] = v;
        }
        __syncthreads();
#pragma unroll
        for (int kk = 0; kk < 16; ++kk) {
            float a[4], b[4];
#pragma unroll
            for (int i = 0; i < 4; ++i) a[i] = As[kk][tr * 4 + i];
#pragma unroll
            for (int j = 0; j < 4; ++j) b[j] = Bs[kk][tc * 4 + j];
#pragma unroll
            for (int i = 0; i < 4; ++i)
#pragma unroll
                for (int j = 0; j < 4; ++j) acc[i][j] += a[i] * b[j];
        }
        __syncthreads();
    }
#pragma unroll
    for (int i = 0; i < 4; ++i) {
        int row = m0 + tr * 4 + i;
#pragma unroll
        for (int j = 0; j < 4; ++j) {
            int col = n0 + tc * 4 + j;
            if (col < F_) {
                float v = acc[i][j];
                if (bias) v += bias[col];
                C[(size_t)row * F_ + col] = v;
            }
        }
    }
}

// ------- fused post GEMM: C[CH,126] = [h | agg | agg*amp | agg*att] @ B[1638,126] + bias ------
__global__ __launch_bounds__(256) void k_gemm_post(const float* __restrict__ hc,
                                                   const float* __restrict__ aggb,
                                                   const float* __restrict__ ampc,
                                                   const float* __restrict__ attc,
                                                   const float* __restrict__ B,
                                                   const float* __restrict__ bias,
                                                   float* __restrict__ C) {
    __shared__ float As[16][68];
    __shared__ float Bs[16][64];
    int tid = threadIdx.x;
    int m0 = blockIdx.y * 64;
    int n0 = blockIdx.x * 64;
    int tr = tid >> 4, tc = tid & 15;
    int ar = tid >> 4, ak = tid & 15;
    int br = tid >> 6, bn = tid & 63;
    float acc[4][4] = {};
    for (int k0 = 0; k0 < 1638; k0 += 16) {
#pragma unroll
        for (int i = 0; i < 4; ++i) {
            int row = m0 + ar + 16 * i;
            int k = k0 + ak;
            float v = 0.f;
            if (k < 126) {
                v = hc[(size_t)row * F_ + k];
            } else if (k < 1638) {
                int kk = k - 126;
                int blk = kk / 504;          // 0: agg, 1: agg*amp, 2: agg*att
                int ka  = kk - blk * 504;
                v = aggb[(size_t)row * 504 + ka];
                if (blk == 1) v *= ampc[row];
                else if (blk == 2) v *= attc[row];
            }
            As[ak][ar + 16 * i] = v;
        }
#pragma unroll
        for (int i = 0; i < 4; ++i) {
            int kk = k0 + br + 4 * i;
            float v = 0.f;
            if (kk < 1638 && n0 + bn < F_) v = B[(size_t)kk * F_ + n0 + bn];
            Bs[br + 4 * i][bn] = v;
        }
        __syncthreads();
#pragma unroll
        for (int kk = 0; kk < 16; ++kk) {
            float a[4], b[4];
#pragma unroll
            for (int i = 0; i < 4; ++i) a[i] = As[kk][tr * 4 + i];
#pragma unroll
            for (int j = 0; j < 4; ++j) b[j] = Bs[kk][tc * 4 + j];
#pragma unroll
            for (int i = 0; i < 4; ++i)
#pragma unroll
                for (int j = 0; j < 4; ++j) acc[i][j] += a[i] * b[j];
        }
        __syncthreads();
    }
#pragma unroll
    for (int i = 0; i < 4; ++i) {
        int row = m0 + tr * 4 + i;
#pragma unroll
        for (int j = 0; j < 4; ++j) {
            int col = n0 + tc * 4 + j;
            if (col < F_) C[(size_t)row * F_ + col] = acc[i][j] + bias[col];
        }
    }
}

// ---------------- edge aggregation (one block per node; chunk-local) ----------------
// m_e = Pd[dst] + (Ps[src] + etab[attr]) = c + v ;  agg = [c+mean(v), c+min(v), c+max(v), std(v)]
__global__ void k_aggregate(const float* __restrict__ Pd, const float* __restrict__ Ps,
                            const float* __restrict__ etab_l,
                            const int* __restrict__ deg, const int* __restrict__ rstart,
                            const int* __restrict__ epack, const float* __restrict__ invc,
                            float* __restrict__ agg, int n_base) {
    int nl = blockIdx.x;          // chunk-local node
    int n  = n_base + nl;         // global node
    int f  = threadIdx.x;
    if (f >= F_) return;
    float* arow = agg + (size_t)nl * (4 * F_);
    int dg = deg[n];
    if (dg == 0) {
        arow[f] = 0.f; arow[F_ + f] = 0.f; arow[2 * F_ + f] = 0.f;
        arow[3 * F_ + f] = sqrtf(EPSV);
        return;
    }
    int rs = rstart[n];
    float c = Pd[(size_t)nl * F_ + f];
    float sum = 0.f, sumsq = 0.f, vmin = 3.4e38f, vmax = -3.4e38f;
    for (int e = 0; e < dg; ++e) {
        int pk = epack[rs + e];
        int s  = (pk & 0xFFFFF) - n_base;   // chunk-local src (same graph => same chunk)
        int a  = pk >> 20;
        float v = Ps[(size_t)s * F_ + f] + etab_l[a * F_ + f];
        sum += v; sumsq += v * v;
        vmin = fminf(vmin, v); vmax = fmaxf(vmax, v);
    }
    float ic  = invc[n];
    float mv  = sum * ic;
    float var = sumsq * ic - mv * mv;
    arow[f]          = c + mv;
    arow[F_ + f]     = c + vmin;
    arow[2 * F_ + f] = c + vmax;
    arow[3 * F_ + f] = sqrtf(fmaxf(var, 0.f) + EPSV);
}

// ---------------- BatchNorm stats / apply (in-place on h) ----------------
__global__ void k_bn_stats(const float* __restrict__ X, float* __restrict__ sums) {
    int f = threadIdx.x;
    if (f >= F_) return;
    int r0 = blockIdx.x * 64;
    float s = 0.f, s2 = 0.f;
    for (int r = 0; r < 64; ++r) {
        float v = X[(size_t)(r0 + r) * F_ + f];
        s += v; s2 += v * v;
    }
    atomicAdd(&sums[f], s);
    atomicAdd(&sums[F_ + f], s2);
}

__global__ void k_bn_apply(float* __restrict__ H, const float* __restrict__ sums,
                           const float* __restrict__ g, const float* __restrict__ b) {
    int idx = blockIdx.x * blockDim.x + threadIdx.x;
    if (idx >= NN * F_) return;
    int f = idx % F_;
    float mu  = sums[f] * (1.f / NN);
    float var = sums[F_ + f] * (1.f / NN) - mu * mu;
    float v = g[f] * (H[idx] - mu) * rsqrtf(var + EPSV) + b[f];
    H[idx] = fmaxf(v, 0.f);
}

// ---------------- pool (per-graph sum) + 4-layer MLP head ----------------
__global__ __launch_bounds__(128) void k_pool_mlp(const float* __restrict__ h,
        const float* __restrict__ w1, const float* __restrict__ b1,
        const float* __restrict__ w2, const float* __restrict__ b2,
        const float* __restrict__ w3, const float* __restrict__ b3,
        const float* __restrict__ w4, const float* __restrict__ b4,
        float* __restrict__ out) {
    int g = blockIdx.x;
    __shared__ float p[F_];
    __shared__ float z1[100];
    __shared__ float z2[50];
    __shared__ float z3[25];
    int t = threadIdx.x;
    if (t < F_) {
        float s = 0.f;
        const float* hb = h + (size_t)g * NPG * F_;
        for (int r = 0; r < NPG; ++r) s += hb[r * F_ + t];
        p[t] = s;
    }
    __syncthreads();
    if (t < 100) {
        float s = b1[t];
        for (int c = 0; c < F_; ++c) s += p[c] * w1[c * 100 + t];
        z1[t] = fmaxf(s, 0.f);
    }
    __syncthreads();
    if (t < 50) {
        float s = b2[t];
        for (int c = 0; c < 100; ++c) s += z1[c] * w2[c * 50 + t];
        z2[t] = fmaxf(s, 0.f);
    }
    __syncthreads();
    if (t < 25) {
        float s = b3[t];
        for (int c = 0; c < 50; ++c) s += z2[c] * w3[c * 25 + t];
        z3[t] = fmaxf(s, 0.f);
    }
    __syncthreads();
    if (t == 0) {
        float s = b4[0];
        for (int c = 0; c < 25; ++c) s += z3[c] * w4[c];
        out[g] = s;
    }
}

extern "C" void kernel_launch(void* const* d_in, const int* in_sizes, int n_in,
                              void* d_out, int out_size, void* d_ws, size_t ws_size,
                              hipStream_t stream) {
    const float* x        = (const float*)d_in[0];
    const int*   ei       = (const int*)d_in[1];
    const int*   src      = ei;
    const int*   dst      = ei + EE;
    const int*   eattr    = (const int*)d_in[2];
    const int*   deg_hist = (const int*)d_in[4];
    const float* emb1_w = (const float*)d_in[5];
    const float* emb1_b = (const float*)d_in[6];
    const float* edge_tab = (const float*)d_in[7];
    const float* enc_w  = (const float*)d_in[8];
    const float* enc_b  = (const float*)d_in[9];
    const float* pre_w  = (const float*)d_in[10];
    const float* pre_b  = (const float*)d_in[11];
    const float* post_w = (const float*)d_in[12];
    const float* post_b = (const float*)d_in[13];
    const float* lin_w  = (const float*)d_in[14];
    const float* lin_b  = (const float*)d_in[15];
    const float* bn_g   = (const float*)d_in[16];
    const float* bn_b   = (const float*)d_in[17];
    const float* w1 = (const float*)d_in[18];
    const float* b1 = (const float*)d_in[19];
    const float* w2 = (const float*)d_in[20];
    const float* b2 = (const float*)d_in[21];
    const float* w3 = (const float*)d_in[22];
    const float* b3 = (const float*)d_in[23];
    const float* w4 = (const float*)d_in[24];
    const float* b4 = (const float*)d_in[25];
    float* out = (float*)d_out;

    // workspace layout (~120.5 MiB total)
    float* ws   = (float*)d_ws;
    float* h    = ws;                        // NN*F          = 16,257,024
    float* Pd   = h    + (size_t)NN * F_;    // CH*F          =  2,032,128
    float* Ps   = Pd   + (size_t)CH * F_;    // CH*F          =  2,032,128
    float* aggb = Ps   + (size_t)CH * F_;    // CH*4F         =  8,128,512
    float* outA = aggb + (size_t)CH * 4 * F_;// CH*F          =  2,032,128
    float* etab = outA + (size_t)CH * F_;    // 4*10*F        =      5,040
    float* invc = etab + 4 * 10 * F_;        // NN
    float* ampv = invc + NN;                 // NN
    float* attv = ampv + NN;                 // NN
    float* bnsums = attv + NN;               // 256
    int*   deg    = (int*)(bnsums + 256);    // NN
    int*   rstart = deg + NN;                // NN
    int*   epack  = rstart + NN;             // EE

    k_embed<<<(NN * F_ + 255) / 256, 256, 0, stream>>>(x, emb1_w, emb1_b, h);
    k_build_csr<<<G_, 128, 0, stream>>>(src, dst, eattr, deg, rstart, epack);
    k_node_scalars<<<(NN + 255) / 256, 256, 0, stream>>>(deg, deg_hist, invc, ampv, attv);
    k_build_etab<<<40, 128, 0, stream>>>(edge_tab, enc_w, enc_b, pre_w, pre_b, etab);

    for (int l = 0; l < 4; ++l) {
        const float* Wi = pre_w + (size_t)l * 378 * F_;           // rows 0..125   (h[dst])
        const float* Wj = pre_w + ((size_t)l * 378 + 126) * F_;   // rows 126..251 (h[src])
        const float* Bp = post_w + (size_t)l * 1638 * F_;         // full post block

        for (int c = 0; c < NCHUNK; ++c) {
            float* hc = h + (size_t)c * CH * F_;
            int    nb = c * CH;
            k_gemm_plain<<<dim3(2, CH / 64), 256, 0, stream>>>(hc, Wi, Pd, CH, F_, nullptr);
            k_gemm_plain<<<dim3(2, CH / 64), 256, 0, stream>>>(hc, Wj, Ps, CH, F_, nullptr);
            k_aggregate<<<CH, 128, 0, stream>>>(Pd, Ps, etab + l * 10 * F_, deg, rstart,
                                                epack, invc, aggb, nb);
            k_gemm_post<<<dim3(2, CH / 64), 256, 0, stream>>>(hc, aggb, ampv + nb, attv + nb,
                                                              Bp, post_b + l * F_, outA);
            // lin; write back into h chunk (h rows of this chunk fully consumed above)
            k_gemm_plain<<<dim3(2, CH / 64), 256, 0, stream>>>(outA, lin_w + (size_t)l * F_ * F_,
                                                               hc, CH, F_, lin_b + l * F_);
        }
        // BatchNorm + ReLU in place on h
        hipMemsetAsync(bnsums, 0, 256 * sizeof(float), stream);
        k_bn_stats<<<NN / 64, 128, 0, stream>>>(h, bnsums);
        k_bn_apply<<<(NN * F_ + 255) / 256, 256, 0, stream>>>(h, bnsums,
                                                              bn_g + l * F_, bn_b + l * F_);
    }

    k_pool_mlp<<<G_, 128, 0, stream>>>(h, w1, b1, w2, b2, w3, b3, w4, b4, out);
}

// Round 6
// 1862.988 us; speedup vs baseline: 6.9753x; 6.9753x over previous
//
#include <hip/hip_runtime.h>
#include <math.h>

#define G_    1024
#define NPG   126
#define EPG   450
#define NN    (G_*NPG)      // 129024
#define EE    (G_*EPG)      // 460800
#define F_    126
#define EPSV  1e-5f
#define NCHUNK 4
#define CH    (NN/NCHUNK)   // 32256 nodes = 256 graphs per chunk

#define KSTEPS_POST 52                 // virtual K = 128 + 3*512 = 1664
#define POSTB_SZ (KSTEPS_POST*8*64*8)  // 212992 shorts per layer
#define SMALLB_SZ (4*8*64*8)           // 16384 shorts per matrix per layer

typedef unsigned short u16;
typedef unsigned int   u32;
typedef __attribute__((ext_vector_type(8))) short bf8v;   // 8 bf16 in 4 VGPRs
typedef __attribute__((ext_vector_type(4))) float f4v;

union U4 { bf8v v; u32 a[4]; };

__device__ __forceinline__ u16 f2b(float f) {              // RNE f32 -> bf16
    u32 u = __float_as_uint(f);
    u += 0x7FFFu + ((u >> 16) & 1u);
    return (u16)(u >> 16);
}
__device__ __forceinline__ float b2f(u16 s) { return __uint_as_float(((u32)s) << 16); }

__device__ __forceinline__ bf8v scale8(const U4& r, float s) {
    U4 o;
#pragma unroll
    for (int i = 0; i < 4; ++i) {
        u32 u = r.a[i];
        float lo = __uint_as_float(u << 16) * s;
        float hi = __uint_as_float(u & 0xFFFF0000u) * s;
        u32 pk;
        asm("v_cvt_pk_bf16_f32 %0, %1, %2" : "=v"(pk) : "v"(lo), "v"(hi));
        o.a[i] = pk;
    }
    return o.v;
}

// ---------------- node embedding: hb = bf16(x @ emb1_w + emb1_b), padded to 128 cols --------
__global__ void k_embed(const float* __restrict__ x, const float* __restrict__ w,
                        const float* __restrict__ b, u16* __restrict__ hb) {
    int idx = blockIdx.x * blockDim.x + threadIdx.x;
    if (idx >= NN * 128) return;
    int n = idx >> 7, f = idx & 127;
    if (f >= F_) { hb[idx] = 0; return; }
    float v = b[f];
#pragma unroll
    for (int c = 0; c < 5; ++c) v += x[n * 5 + c] * w[c * F_ + f];
    hb[idx] = f2b(v);
}

// ---------------- per-graph CSR build ----------------
__global__ void k_build_csr(const int* __restrict__ src, const int* __restrict__ dst,
                            const int* __restrict__ attr,
                            int* __restrict__ deg, int* __restrict__ rstart,
                            int* __restrict__ epack) {
    int g = blockIdx.x;
    __shared__ int scnt[NPG];
    __shared__ int spos[NPG];
    int t = threadIdx.x;
    for (int j = t; j < NPG; j += blockDim.x) scnt[j] = 0;
    __syncthreads();
    int e0 = g * EPG;
    for (int i = t; i < EPG; i += blockDim.x) {
        int dl = dst[e0 + i] - g * NPG;
        atomicAdd(&scnt[dl], 1);
    }
    __syncthreads();
    if (t == 0) {
        int run = 0;
        for (int j = 0; j < NPG; ++j) { spos[j] = run; run += scnt[j]; }
    }
    __syncthreads();
    for (int j = t; j < NPG; j += blockDim.x) {
        deg[g * NPG + j]    = scnt[j];
        rstart[g * NPG + j] = e0 + spos[j];
    }
    __syncthreads();
    for (int j = t; j < NPG; j += blockDim.x) scnt[j] = 0;
    __syncthreads();
    for (int i = t; i < EPG; i += blockDim.x) {
        int e  = e0 + i;
        int dl = dst[e] - g * NPG;
        int p  = atomicAdd(&scnt[dl], 1);
        epack[e0 + spos[dl] + p] = src[e] | (attr[e] << 20);  // src < 2^20, attr < 16
    }
}

// ---------------- per-node degree scalers ----------------
__global__ void k_node_scalars(const int* __restrict__ deg, const int* __restrict__ deg_hist,
                               float* __restrict__ invc, float* __restrict__ ampv,
                               float* __restrict__ attv) {
    int n = blockIdx.x * blockDim.x + threadIdx.x;
    if (n >= NN) return;
    float sum = 0.f, sl = 0.f;
#pragma unroll
    for (int b = 0; b < 5; ++b) {
        float dh = (float)deg_hist[b];
        sum += dh;
        sl  += dh * logf((float)b + 1.f);
    }
    float avg_log = sl / sum;
    float c  = (float)deg[n];
    float cm = fmaxf(c, 1.f);
    invc[n] = 1.f / cm;
    float la = logf(cm + 1.f);
    ampv[n] = la / avg_log;
    attv[n] = avg_log / la;
}

// ---------------- edge-attr table (fp32): etab[l][a][f] ----------------
__global__ void k_build_etab(const float* __restrict__ edge_tab, const float* __restrict__ enc_w,
                             const float* __restrict__ enc_b, const float* __restrict__ pre_w,
                             const float* __restrict__ pre_b, float* __restrict__ etab) {
    int l = blockIdx.x / 10, a = blockIdx.x % 10;
    __shared__ float tmp[F_];
    int t = threadIdx.x;
    if (t < F_) {
        float s = enc_b[l * F_ + t];
        for (int c = 0; c < 50; ++c) s += edge_tab[a * 50 + c] * enc_w[(l * 50 + c) * F_ + t];
        tmp[t] = s;
    }
    __syncthreads();
    if (t < F_) {
        float s = pre_b[l * F_ + t];
        for (int j = 0; j < F_; ++j) s += tmp[j] * pre_w[((size_t)l * 378 + 252 + j) * F_ + t];
        etab[(l * 10 + a) * F_ + t] = s;
    }
}

// ---------------- B prep: frag-linear bf16 layout for direct b-frag dwordx4 loads ----------
// Bv[((ks*8 + panel)*64 + lane)*8 + j] = B[ks*32 + (lane>>4)*8 + j][panel*16 + (lane&15)]
__global__ void k_prep_B128(const float* __restrict__ pre_w, const float* __restrict__ lin_w,
                            u16* __restrict__ wiB, u16* __restrict__ wjB, u16* __restrict__ linB) {
    int idx = blockIdx.x * 256 + threadIdx.x;        // 0..16383
    int y = blockIdx.y;                              // 0..11
    int l = y & 3, ty = y >> 2;
    const float* W = (ty == 0) ? pre_w + (size_t)l * 378 * F_
                   : (ty == 1) ? pre_w + ((size_t)l * 378 + 126) * F_
                               : lin_w + (size_t)l * F_ * F_;
    u16* out = ((ty == 0) ? wiB : (ty == 1) ? wjB : linB) + (size_t)l * SMALLB_SZ;
    int j = idx & 7, lane = (idx >> 3) & 63, pnl = (idx >> 9) & 7, ks = idx >> 12;
    int k = ks * 32 + (lane >> 4) * 8 + j;
    int c = pnl * 16 + (lane & 15);
    float v = (k < F_ && c < F_) ? W[(size_t)k * F_ + c] : 0.f;
    out[idx] = f2b(v);
}

__global__ void k_prep_Bpost(const float* __restrict__ post_w, u16* __restrict__ postB) {
    int idx = blockIdx.x * 256 + threadIdx.x;        // 0..212991
    if (idx >= POSTB_SZ) return;
    int l = blockIdx.y;
    int j = idx & 7, lane = (idx >> 3) & 63, pnl = (idx >> 9) & 7, ks = idx >> 12;
    int vk = ks * 32 + (lane >> 4) * 8 + j;
    int c  = pnl * 16 + (lane & 15);
    int rk = -1;
    if (vk < 128) { if (vk < F_) rk = vk; }
    else { int v = vk - 128, seg = v >> 9, ka = v & 511; if (ka < 504) rk = F_ + seg * 504 + ka; }
    float val = (rk >= 0 && c < F_) ? post_w[((size_t)l * 1638 + rk) * F_ + c] : 0.f;
    postB[(size_t)l * POSTB_SZ + idx] = f2b(val);
}

// ---------------- MFMA GEMM, no LDS: C[M,126] = A @ B (+bias), A virtual-K if FUSED ---------
// block: 256 thr = 4 waves, tile 64 rows x 128 cols; wave tile 32x64.
template<int FUSED, int OF32>
__global__ __launch_bounds__(256) void k_gemm_mfma(
        const u16* __restrict__ A0,      // [M][128] bf16 (hb or outA)
        const u16* __restrict__ AG,      // [M][512] bf16 agg (FUSED only)
        const float* __restrict__ amp, const float* __restrict__ att,
        const u16* __restrict__ Bv0, const u16* __restrict__ Bv1,
        const float* __restrict__ bias0, const float* __restrict__ bias1,
        void* __restrict__ C0, void* __restrict__ C1, int ksteps) {
    const u16* Bv = blockIdx.y ? Bv1 : Bv0;
    const float* bias = blockIdx.y ? bias1 : bias0;
    void* C = blockIdx.y ? C1 : C0;
    int lane = threadIdx.x & 63, wid = threadIdx.x >> 6;
    int g = lane >> 4, r15 = lane & 15;
    int wr = (wid >> 1) * 32, wc = (wid & 1) * 64;
    size_t row0 = (size_t)blockIdx.x * 64 + wr + r15;
    const u16* a0p = A0 + row0 * 128 + g * 8;
    const u16* a1p = a0p + 16 * 128;
    const u16* g0p = nullptr; const u16* g1p = nullptr;
    float am0 = 1.f, am1 = 1.f, at0 = 1.f, at1 = 1.f;
    if (FUSED) {
        g0p = AG + row0 * 512 + g * 8;
        g1p = g0p + 16 * 512;
        am0 = amp[row0]; am1 = amp[row0 + 16];
        at0 = att[row0]; at1 = att[row0 + 16];
    }
    const u16* bp = Bv + ((size_t)(wc >> 4) * 64 + lane) * 8;
    f4v acc[2][4];
#pragma unroll
    for (int i = 0; i < 2; ++i)
#pragma unroll
        for (int j = 0; j < 4; ++j) acc[i][j] = (f4v){0.f, 0.f, 0.f, 0.f};

    for (int ks = 0; ks < ksteps; ++ks) {
        const u16* bk = bp + (size_t)ks * 4096;
        bf8v b0 = *(const bf8v*)(bk);
        bf8v b1 = *(const bf8v*)(bk + 512);
        bf8v b2 = *(const bf8v*)(bk + 1024);
        bf8v b3 = *(const bf8v*)(bk + 1536);
        bf8v a0, a1;
        if (!FUSED) {
            a0 = *(const bf8v*)(a0p + ks * 32);
            a1 = *(const bf8v*)(a1p + ks * 32);
        } else {
            int kb = ks * 32;
            if (kb < 128) {
                a0 = *(const bf8v*)(a0p + kb);
                a1 = *(const bf8v*)(a1p + kb);
            } else {
                int v = kb - 128;
                int seg = v >> 9;
                int ka = v & 511;
                U4 r0, r1;
                r0.v = *(const bf8v*)(g0p + ka);
                r1.v = *(const bf8v*)(g1p + ka);
                if (seg == 0) { a0 = r0.v; a1 = r1.v; }
                else {
                    float s0 = (seg == 1) ? am0 : at0;
                    float s1 = (seg == 1) ? am1 : at1;
                    a0 = scale8(r0, s0);
                    a1 = scale8(r1, s1);
                }
            }
        }
#pragma unroll
        for (int fc = 0; fc < 4; ++fc) {
            bf8v bb = (fc == 0) ? b0 : (fc == 1) ? b1 : (fc == 2) ? b2 : b3;
            acc[0][fc] = __builtin_amdgcn_mfma_f32_16x16x32_bf16(a0, bb, acc[0][fc], 0, 0, 0);
            acc[1][fc] = __builtin_amdgcn_mfma_f32_16x16x32_bf16(a1, bb, acc[1][fc], 0, 0, 0);
        }
    }
    // epilogue: C/D map col=lane&15, row=(lane>>4)*4+reg  [verified]
    int erow = blockIdx.x * 64 + wr + g * 4;
    int ecol = wc + r15;
#pragma unroll
    for (int fr = 0; fr < 2; ++fr) {
#pragma unroll
        for (int fc = 0; fc < 4; ++fc) {
            int col = ecol + fc * 16;
            float bv = (bias && col < F_) ? bias[col] : 0.f;
#pragma unroll
            for (int r = 0; r < 4; ++r) {
                int row = erow + fr * 16 + r;
                float val = acc[fr][fc][r] + bv;
                if (OF32) {
                    if (col < F_) ((float*)C)[(size_t)row * 128 + col] = val;
                } else {
                    ((u16*)C)[(size_t)row * 128 + col] = (col < F_) ? f2b(val) : (u16)0;
                }
            }
        }
    }
}

// ---------------- edge aggregation: aggb[nl][512] bf16 = [mean+c | min+c | max+c | std | 0pad]
__global__ void k_aggregate(const float* __restrict__ Pd, const float* __restrict__ Ps,
                            const float* __restrict__ etab_l,
                            const int* __restrict__ deg, const int* __restrict__ rstart,
                            const int* __restrict__ epack, const float* __restrict__ invc,
                            u16* __restrict__ aggb, int n_base) {
    int nl = blockIdx.x;
    int n  = n_base + nl;
    int f  = threadIdx.x;
    u16* arow = aggb + (size_t)nl * 512;
    if (f < 8) arow[504 + f] = 0;
    if (f >= F_) return;
    int dg = deg[n];
    if (dg == 0) {
        arow[f] = 0; arow[F_ + f] = 0; arow[2 * F_ + f] = 0;
        arow[3 * F_ + f] = f2b(sqrtf(EPSV));
        return;
    }
    int rs = rstart[n];
    float c = Pd[(size_t)nl * 128 + f];
    float sum = 0.f, sumsq = 0.f, vmin = 3.4e38f, vmax = -3.4e38f;
    for (int e = 0; e < dg; ++e) {
        int pk = epack[rs + e];
        int s  = (pk & 0xFFFFF) - n_base;
        int a  = pk >> 20;
        float v = Ps[(size_t)s * 128 + f] + etab_l[a * F_ + f];
        sum += v; sumsq += v * v;
        vmin = fminf(vmin, v); vmax = fmaxf(vmax, v);
    }
    float ic  = invc[n];
    float mv  = sum * ic;
    float var = sumsq * ic - mv * mv;
    arow[f]          = f2b(c + mv);
    arow[F_ + f]     = f2b(c + vmin);
    arow[2 * F_ + f] = f2b(c + vmax);
    arow[3 * F_ + f] = f2b(sqrtf(fmaxf(var, 0.f) + EPSV));
}

// ---------------- BatchNorm stats / apply (in-place on hb, bf16) ----------------
__global__ void k_bn_stats(const u16* __restrict__ hb, float* __restrict__ sums) {
    int f = threadIdx.x;
    if (f >= F_) return;
    int r0 = blockIdx.x * 64;
    float s = 0.f, s2 = 0.f;
    for (int r = 0; r < 64; ++r) {
        float v = b2f(hb[(size_t)(r0 + r) * 128 + f]);
        s += v; s2 += v * v;
    }
    atomicAdd(&sums[f], s);
    atomicAdd(&sums[F_ + f], s2);
}

__global__ void k_bn_apply(u16* __restrict__ hb, const float* __restrict__ sums,
                           const float* __restrict__ g, const float* __restrict__ b) {
    int n = blockIdx.x;
    int f = threadIdx.x;
    if (f >= F_) return;
    float mu  = sums[f] * (1.f / NN);
    float var = sums[F_ + f] * (1.f / NN) - mu * mu;
    float v = g[f] * (b2f(hb[(size_t)n * 128 + f]) - mu) * rsqrtf(var + EPSV) + b[f];
    hb[(size_t)n * 128 + f] = f2b(fmaxf(v, 0.f));
}

// ---------------- pool (per-graph sum) + 4-layer MLP head (fp32) ----------------
__global__ __launch_bounds__(128) void k_pool_mlp(const u16* __restrict__ hb,
        const float* __restrict__ w1, const float* __restrict__ b1,
        const float* __restrict__ w2, const float* __restrict__ b2,
        const float* __restrict__ w3, const float* __restrict__ b3,
        const float* __restrict__ w4, const float* __restrict__ b4,
        float* __restrict__ out) {
    int g = blockIdx.x;
    __shared__ float p[F_];
    __shared__ float z1[100];
    __shared__ float z2[50];
    __shared__ float z3[25];
    int t = threadIdx.x;
    if (t < F_) {
        float s = 0.f;
        const u16* hbase = hb + (size_t)g * NPG * 128;
        for (int r = 0; r < NPG; ++r) s += b2f(hbase[(size_t)r * 128 + t]);
        p[t] = s;
    }
    __syncthreads();
    if (t < 100) {
        float s = b1[t];
        for (int c = 0; c < F_; ++c) s += p[c] * w1[c * 100 + t];
        z1[t] = fmaxf(s, 0.f);
    }
    __syncthreads();
    if (t < 50) {
        float s = b2[t];
        for (int c = 0; c < 100; ++c) s += z1[c] * w2[c * 50 + t];
        z2[t] = fmaxf(s, 0.f);
    }
    __syncthreads();
    if (t < 25) {
        float s = b3[t];
        for (int c = 0; c < 50; ++c) s += z2[c] * w3[c * 25 + t];
        z3[t] = fmaxf(s, 0.f);
    }
    __syncthreads();
    if (t == 0) {
        float s = b4[0];
        for (int c = 0; c < 25; ++c) s += z3[c] * w4[c];
        out[g] = s;
    }
}

extern "C" void kernel_launch(void* const* d_in, const int* in_sizes, int n_in,
                              void* d_out, int out_size, void* d_ws, size_t ws_size,
                              hipStream_t stream) {
    const float* x        = (const float*)d_in[0];
    const int*   ei       = (const int*)d_in[1];
    const int*   src      = ei;
    const int*   dst      = ei + EE;
    const int*   eattr    = (const int*)d_in[2];
    const int*   deg_hist = (const int*)d_in[4];
    const float* emb1_w = (const float*)d_in[5];
    const float* emb1_b = (const float*)d_in[6];
    const float* edge_tab = (const float*)d_in[7];
    const float* enc_w  = (const float*)d_in[8];
    const float* enc_b  = (const float*)d_in[9];
    const float* pre_w  = (const float*)d_in[10];
    const float* pre_b  = (const float*)d_in[11];
    const float* post_w = (const float*)d_in[12];
    const float* post_b = (const float*)d_in[13];
    const float* lin_w  = (const float*)d_in[14];
    const float* lin_b  = (const float*)d_in[15];
    const float* bn_g   = (const float*)d_in[16];
    const float* bn_b   = (const float*)d_in[17];
    const float* w1 = (const float*)d_in[18];
    const float* b1 = (const float*)d_in[19];
    const float* w2 = (const float*)d_in[20];
    const float* b2 = (const float*)d_in[21];
    const float* w3 = (const float*)d_in[22];
    const float* b3 = (const float*)d_in[23];
    const float* w4 = (const float*)d_in[24];
    const float* b4 = (const float*)d_in[25];
    float* out = (float*)d_out;

    // ---- workspace layout (~114 MiB) ----
    char* base = (char*)d_ws;
    size_t o = 0;
    auto alloc = [&](size_t bytes) { char* r = base + o; o = (o + bytes + 255) & ~(size_t)255; return r; };
    u16*  hb    = (u16*)  alloc((size_t)NN * 128 * 2);
    float* Pd   = (float*)alloc((size_t)CH * 128 * 4);
    float* Ps   = (float*)alloc((size_t)CH * 128 * 4);
    u16*  aggb  = (u16*)  alloc((size_t)CH * 512 * 2);
    u16*  outA  = (u16*)  alloc((size_t)CH * 128 * 2);
    float* etab = (float*)alloc(4 * 10 * F_ * 4);
    float* invc = (float*)alloc((size_t)NN * 4);
    float* ampv = (float*)alloc((size_t)NN * 4);
    float* attv = (float*)alloc((size_t)NN * 4);
    float* bnsums = (float*)alloc(1024);
    int*  deg    = (int*)alloc((size_t)NN * 4);
    int*  rstart = (int*)alloc((size_t)NN * 4);
    int*  epack  = (int*)alloc((size_t)EE * 4);
    u16*  wiB   = (u16*)alloc((size_t)4 * SMALLB_SZ * 2);
    u16*  wjB   = (u16*)alloc((size_t)4 * SMALLB_SZ * 2);
    u16*  linB  = (u16*)alloc((size_t)4 * SMALLB_SZ * 2);
    u16*  postB = (u16*)alloc((size_t)4 * POSTB_SZ * 2);

    // ---- setup ----
    k_embed<<<(NN * 128 + 255) / 256, 256, 0, stream>>>(x, emb1_w, emb1_b, hb);
    k_build_csr<<<G_, 128, 0, stream>>>(src, dst, eattr, deg, rstart, epack);
    k_node_scalars<<<(NN + 255) / 256, 256, 0, stream>>>(deg, deg_hist, invc, ampv, attv);
    k_build_etab<<<40, 128, 0, stream>>>(edge_tab, enc_w, enc_b, pre_w, pre_b, etab);
    k_prep_B128<<<dim3(SMALLB_SZ / 256, 12), 256, 0, stream>>>(pre_w, lin_w, wiB, wjB, linB);
    k_prep_Bpost<<<dim3((POSTB_SZ + 255) / 256, 4), 256, 0, stream>>>(post_w, postB);

    for (int l = 0; l < 4; ++l) {
        for (int c = 0; c < NCHUNK; ++c) {
            u16* hc = hb + (size_t)c * CH * 128;
            int  nb = c * CH;
            // Pd = hc@Wi, Ps = hc@Wj (fp32 out, one dual launch)
            k_gemm_mfma<0, 1><<<dim3(CH / 64, 2), 256, 0, stream>>>(
                hc, nullptr, nullptr, nullptr,
                wiB + (size_t)l * SMALLB_SZ, wjB + (size_t)l * SMALLB_SZ,
                nullptr, nullptr, Pd, Ps, 4);
            k_aggregate<<<CH, 128, 0, stream>>>(Pd, Ps, etab + l * 10 * F_, deg, rstart,
                                                epack, invc, aggb, nb);
            // outA = [hc | agg | agg*amp | agg*att] @ post_w + post_b  (virtual K=1664)
            k_gemm_mfma<1, 0><<<dim3(CH / 64, 1), 256, 0, stream>>>(
                hc, aggb, ampv + nb, attv + nb,
                postB + (size_t)l * POSTB_SZ, postB + (size_t)l * POSTB_SZ,
                post_b + l * F_, post_b + l * F_, outA, outA, KSTEPS_POST);
            // hc = outA @ lin_w + lin_b (bf16, in place into hb chunk)
            k_gemm_mfma<0, 0><<<dim3(CH / 64, 1), 256, 0, stream>>>(
                outA, nullptr, nullptr, nullptr,
                linB + (size_t)l * SMALLB_SZ, linB + (size_t)l * SMALLB_SZ,
                lin_b + l * F_, lin_b + l * F_, hc, hc, 4);
        }
        // BatchNorm + ReLU in place on hb
        hipMemsetAsync(bnsums, 0, 1024, stream);
        k_bn_stats<<<NN / 64, 128, 0, stream>>>(hb, bnsums);
        k_bn_apply<<<NN, 128, 0, stream>>>(hb, bnsums, bn_g + l * F_, bn_b + l * F_);
    }

    k_pool_mlp<<<G_, 128, 0, stream>>>(hb, w1, b1, w2, b2, w3, b3, w4, b4, out);
}

// Round 7
// 1722.146 us; speedup vs baseline: 7.5458x; 1.0818x over previous
//
#include <hip/hip_runtime.h>
#include <math.h>

#define G_    1024
#define NPG   126
#define EPG   450
#define NN    (G_*NPG)      // 129024
#define EE    (G_*EPG)      // 460800
#define F_    126
#define EPSV  1e-5f
#define NCHUNK 4
#define CH    (NN/NCHUNK)   // 32256 nodes = 256 graphs per chunk

#define KSTEPS_POST 52                 // 4 (h) + 3*16 (agg segments)
#define POSTB_SZ (KSTEPS_POST*8*64*8)  // 212992 shorts per layer
#define SMALLB_SZ (4*8*64*8)           // 16384 shorts per matrix per layer

typedef unsigned short u16;
typedef unsigned int   u32;
typedef __attribute__((ext_vector_type(8))) short bf8v;   // 8 bf16 in 4 VGPRs
typedef __attribute__((ext_vector_type(4))) float f4v;

union U4 { bf8v v; u32 a[4]; };

__device__ __forceinline__ u16 f2b(float f) {              // RNE f32 -> bf16
    u32 u = __float_as_uint(f);
    u += 0x7FFFu + ((u >> 16) & 1u);
    return (u16)(u >> 16);
}
__device__ __forceinline__ float b2f(u16 s) { return __uint_as_float(((u32)s) << 16); }
__device__ __forceinline__ float b2f_lo(u32 u) { return __uint_as_float(u << 16); }
__device__ __forceinline__ float b2f_hi(u32 u) { return __uint_as_float(u & 0xFFFF0000u); }

// ---------------- node embedding: hb = bf16(x @ emb1_w + emb1_b), short8 stores ----------
__global__ void k_embed(const float* __restrict__ x, const float* __restrict__ w,
                        const float* __restrict__ b, u16* __restrict__ hb) {
    int idx = (blockIdx.x * 256 + threadIdx.x) * 8;
    if (idx >= NN * 128) return;
    int n = idx >> 7, f0 = idx & 127;
    float xr[5];
#pragma unroll
    for (int c = 0; c < 5; ++c) xr[c] = x[n * 5 + c];
    float v[8];
#pragma unroll
    for (int j = 0; j < 8; ++j) {
        int f = f0 + j;
        float s = 0.f;
        if (f < F_) {
            s = b[f];
#pragma unroll
            for (int c = 0; c < 5; ++c) s += xr[c] * w[c * F_ + f];
        }
        v[j] = s;
    }
    U4 o;
#pragma unroll
    for (int i = 0; i < 4; ++i) o.a[i] = (u32)f2b(v[2 * i]) | ((u32)f2b(v[2 * i + 1]) << 16);
    *(bf8v*)(hb + idx) = o.v;
}

// ---------------- per-graph CSR build ----------------
__global__ void k_build_csr(const int* __restrict__ src, const int* __restrict__ dst,
                            const int* __restrict__ attr,
                            int* __restrict__ deg, int* __restrict__ rstart,
                            int* __restrict__ epack) {
    int g = blockIdx.x;
    __shared__ int scnt[NPG];
    __shared__ int spos[NPG];
    int t = threadIdx.x;
    for (int j = t; j < NPG; j += blockDim.x) scnt[j] = 0;
    __syncthreads();
    int e0 = g * EPG;
    for (int i = t; i < EPG; i += blockDim.x) {
        int dl = dst[e0 + i] - g * NPG;
        atomicAdd(&scnt[dl], 1);
    }
    __syncthreads();
    if (t == 0) {
        int run = 0;
        for (int j = 0; j < NPG; ++j) { spos[j] = run; run += scnt[j]; }
    }
    __syncthreads();
    for (int j = t; j < NPG; j += blockDim.x) {
        deg[g * NPG + j]    = scnt[j];
        rstart[g * NPG + j] = e0 + spos[j];
    }
    __syncthreads();
    for (int j = t; j < NPG; j += blockDim.x) scnt[j] = 0;
    __syncthreads();
    for (int i = t; i < EPG; i += blockDim.x) {
        int e  = e0 + i;
        int dl = dst[e] - g * NPG;
        int p  = atomicAdd(&scnt[dl], 1);
        epack[e0 + spos[dl] + p] = src[e] | (attr[e] << 20);
    }
}

// ---------------- per-node degree scalers ----------------
__global__ void k_node_scalars(const int* __restrict__ deg, const int* __restrict__ deg_hist,
                               float* __restrict__ invc, float* __restrict__ ampv,
                               float* __restrict__ attv) {
    int n = blockIdx.x * blockDim.x + threadIdx.x;
    if (n >= NN) return;
    float sum = 0.f, sl = 0.f;
#pragma unroll
    for (int b = 0; b < 5; ++b) {
        float dh = (float)deg_hist[b];
        sum += dh;
        sl  += dh * logf((float)b + 1.f);
    }
    float avg_log = sl / sum;
    float c  = (float)deg[n];
    float cm = fmaxf(c, 1.f);
    invc[n] = 1.f / cm;
    float la = logf(cm + 1.f);
    ampv[n] = la / avg_log;
    attv[n] = avg_log / la;
}

// ---------------- edge-attr table (fp32): etab[l][a][f] ----------------
__global__ void k_build_etab(const float* __restrict__ edge_tab, const float* __restrict__ enc_w,
                             const float* __restrict__ enc_b, const float* __restrict__ pre_w,
                             const float* __restrict__ pre_b, float* __restrict__ etab) {
    int l = blockIdx.x / 10, a = blockIdx.x % 10;
    __shared__ float tmp[F_];
    int t = threadIdx.x;
    if (t < F_) {
        float s = enc_b[l * F_ + t];
        for (int c = 0; c < 50; ++c) s += edge_tab[a * 50 + c] * enc_w[(l * 50 + c) * F_ + t];
        tmp[t] = s;
    }
    __syncthreads();
    if (t < F_) {
        float s = pre_b[l * F_ + t];
        for (int j = 0; j < F_; ++j) s += tmp[j] * pre_w[((size_t)l * 378 + 252 + j) * F_ + t];
        etab[(l * 10 + a) * F_ + t] = s;
    }
}

// ---------------- B prep: frag-linear bf16 layout ----------------
// Bv[((ks*8 + panel)*64 + lane)*8 + j] = B[ks*32 + (lane>>4)*8 + j][panel*16 + (lane&15)]
__global__ void k_prep_B128(const float* __restrict__ pre_w, const float* __restrict__ lin_w,
                            u16* __restrict__ wiB, u16* __restrict__ wjB, u16* __restrict__ linB) {
    int idx = blockIdx.x * 256 + threadIdx.x;        // 0..16383
    int y = blockIdx.y;                              // 0..11
    int l = y & 3, ty = y >> 2;
    const float* W = (ty == 0) ? pre_w + (size_t)l * 378 * F_
                   : (ty == 1) ? pre_w + ((size_t)l * 378 + 126) * F_
                               : lin_w + (size_t)l * F_ * F_;
    u16* out = ((ty == 0) ? wiB : (ty == 1) ? wjB : linB) + (size_t)l * SMALLB_SZ;
    int j = idx & 7, lane = (idx >> 3) & 63, pnl = (idx >> 9) & 7, ks = idx >> 12;
    int k = ks * 32 + (lane >> 4) * 8 + j;
    int c = pnl * 16 + (lane & 15);
    float v = (k < F_ && c < F_) ? W[(size_t)k * F_ + c] : 0.f;
    out[idx] = f2b(v);
}

// post B: ks 0..3 = h rows (0..125); ks 4+seg*16+ki = agg segment rows 126+seg*504+ki*32+kk
__global__ void k_prep_Bpost(const float* __restrict__ post_w, u16* __restrict__ postB) {
    int idx = blockIdx.x * 256 + threadIdx.x;
    if (idx >= POSTB_SZ) return;
    int l = blockIdx.y;
    int j = idx & 7, lane = (idx >> 3) & 63, pnl = (idx >> 9) & 7, ks = idx >> 12;
    int c  = pnl * 16 + (lane & 15);
    int kk = (lane >> 4) * 8 + j;    // 0..31
    int rk = -1;
    if (ks < 4) {
        int vk = ks * 32 + kk;
        if (vk < F_) rk = vk;
    } else {
        int seg = (ks - 4) >> 4;
        int ka  = ((ks - 4) & 15) * 32 + kk;
        if (ka < 504) rk = F_ + seg * 504 + ka;
    }
    float val = (rk >= 0 && c < F_) ? post_w[((size_t)l * 1638 + rk) * F_ + c] : 0.f;
    postB[(size_t)l * POSTB_SZ + idx] = f2b(val);
}

// ---------------- small MFMA GEMM (K=128), dual via grid.y, optional fused BN stats --------
template<int OF32, int BNSTAT>
__global__ __launch_bounds__(256) void k_gemm_mfma(
        const u16* __restrict__ A0,
        const u16* __restrict__ Bv0, const u16* __restrict__ Bv1,
        const float* __restrict__ bias0, const float* __restrict__ bias1,
        void* __restrict__ C0, void* __restrict__ C1,
        float* __restrict__ bns) {
    const u16* Bv = blockIdx.y ? Bv1 : Bv0;
    const float* bias = blockIdx.y ? bias1 : bias0;
    void* C = blockIdx.y ? C1 : C0;
    __shared__ float ldsS[128];
    __shared__ float ldsQ[128];
    int tid = threadIdx.x;
    if (BNSTAT) {
        if (tid < 128) { ldsS[tid] = 0.f; ldsQ[tid] = 0.f; }
        __syncthreads();
    }
    int lane = tid & 63, wid = tid >> 6;
    int g = lane >> 4, r15 = lane & 15;
    int wr = (wid >> 1) * 32, wc = (wid & 1) * 64;
    size_t row0 = (size_t)blockIdx.x * 64 + wr + r15;
    const u16* a0p = A0 + row0 * 128 + g * 8;
    const u16* a1p = a0p + 16 * 128;
    const u16* bp = Bv + ((size_t)(wc >> 4) * 64 + lane) * 8;
    f4v acc[2][4];
#pragma unroll
    for (int i = 0; i < 2; ++i)
#pragma unroll
        for (int j = 0; j < 4; ++j) acc[i][j] = (f4v){0.f, 0.f, 0.f, 0.f};

#pragma unroll
    for (int ks = 0; ks < 4; ++ks) {
        bf8v a0 = *(const bf8v*)(a0p + ks * 32);
        bf8v a1 = *(const bf8v*)(a1p + ks * 32);
        const u16* bk = bp + (size_t)ks * 4096;
#pragma unroll
        for (int fc = 0; fc < 4; ++fc) {
            bf8v bb = *(const bf8v*)(bk + fc * 512);
            acc[0][fc] = __builtin_amdgcn_mfma_f32_16x16x32_bf16(a0, bb, acc[0][fc], 0, 0, 0);
            acc[1][fc] = __builtin_amdgcn_mfma_f32_16x16x32_bf16(a1, bb, acc[1][fc], 0, 0, 0);
        }
    }
    int erow = blockIdx.x * 64 + wr + g * 4;
    int ecol = wc + r15;
#pragma unroll
    for (int fc = 0; fc < 4; ++fc) {
        int col = ecol + fc * 16;
        float bv = (bias && col < F_) ? bias[col] : 0.f;
        float s = 0.f, q = 0.f;
#pragma unroll
        for (int fr = 0; fr < 2; ++fr) {
#pragma unroll
            for (int r = 0; r < 4; ++r) {
                int row = erow + fr * 16 + r;
                float val = acc[fr][fc][r] + bv;
                if (BNSTAT) { s += val; q += val * val; }
                if (OF32) {
                    if (col < F_) ((float*)C)[(size_t)row * 128 + col] = val;
                } else {
                    ((u16*)C)[(size_t)row * 128 + col] = (col < F_) ? f2b(val) : (u16)0;
                }
            }
        }
        if (BNSTAT) { atomicAdd(&ldsS[col], s); atomicAdd(&ldsQ[col], q); }
    }
    if (BNSTAT) {
        __syncthreads();
        if (tid < 128) {
            atomicAdd(&bns[tid], ldsS[tid]);
            atomicAdd(&bns[128 + tid], ldsQ[tid]);
        }
    }
}

// ---------------- post GEMM: out = h@B0 + agg@B1 + amp*(agg@B2) + att*(agg@B3) + bias -------
__global__ __launch_bounds__(256) void k_gemm_post(
        const u16* __restrict__ A0,      // [CH][128] h
        const u16* __restrict__ AG,      // [CH][512] agg
        const float* __restrict__ amp, const float* __restrict__ att,
        const u16* __restrict__ Bv, const float* __restrict__ bias,
        u16* __restrict__ C) {
    int lane = threadIdx.x & 63, wid = threadIdx.x >> 6;
    int g = lane >> 4, r15 = lane & 15;
    int wr = (wid >> 1) * 32, wc = (wid & 1) * 64;
    size_t row0 = (size_t)blockIdx.x * 64 + wr + r15;
    const u16* a0p = A0 + row0 * 128 + g * 8;
    const u16* a1p = a0p + 16 * 128;
    const u16* g0p = AG + row0 * 512 + g * 8;
    const u16* g1p = g0p + 16 * 512;
    const u16* bp = Bv + ((size_t)(wc >> 4) * 64 + lane) * 8;
    f4v acc0[2][4], acc1[2][4], acc2[2][4];
#pragma unroll
    for (int i = 0; i < 2; ++i)
#pragma unroll
        for (int j = 0; j < 4; ++j) {
            acc0[i][j] = (f4v){0.f, 0.f, 0.f, 0.f};
            acc1[i][j] = (f4v){0.f, 0.f, 0.f, 0.f};
            acc2[i][j] = (f4v){0.f, 0.f, 0.f, 0.f};
        }
    // h segment (ksteps 0..3)
#pragma unroll
    for (int ks = 0; ks < 4; ++ks) {
        bf8v a0 = *(const bf8v*)(a0p + ks * 32);
        bf8v a1 = *(const bf8v*)(a1p + ks * 32);
        const u16* bk = bp + (size_t)ks * 4096;
#pragma unroll
        for (int fc = 0; fc < 4; ++fc) {
            bf8v bb = *(const bf8v*)(bk + fc * 512);
            acc0[0][fc] = __builtin_amdgcn_mfma_f32_16x16x32_bf16(a0, bb, acc0[0][fc], 0, 0, 0);
            acc0[1][fc] = __builtin_amdgcn_mfma_f32_16x16x32_bf16(a1, bb, acc0[1][fc], 0, 0, 0);
        }
    }
    // agg segments: one A-load feeds 3 B segments
#pragma unroll 2
    for (int ks = 0; ks < 16; ++ks) {
        bf8v a0 = *(const bf8v*)(g0p + ks * 32);
        bf8v a1 = *(const bf8v*)(g1p + ks * 32);
        const u16* bk0 = bp + (size_t)(4 + ks) * 4096;
        const u16* bk1 = bp + (size_t)(20 + ks) * 4096;
        const u16* bk2 = bp + (size_t)(36 + ks) * 4096;
#pragma unroll
        for (int fc = 0; fc < 4; ++fc) {
            bf8v b0 = *(const bf8v*)(bk0 + fc * 512);
            acc0[0][fc] = __builtin_amdgcn_mfma_f32_16x16x32_bf16(a0, b0, acc0[0][fc], 0, 0, 0);
            acc0[1][fc] = __builtin_amdgcn_mfma_f32_16x16x32_bf16(a1, b0, acc0[1][fc], 0, 0, 0);
            bf8v b1 = *(const bf8v*)(bk1 + fc * 512);
            acc1[0][fc] = __builtin_amdgcn_mfma_f32_16x16x32_bf16(a0, b1, acc1[0][fc], 0, 0, 0);
            acc1[1][fc] = __builtin_amdgcn_mfma_f32_16x16x32_bf16(a1, b1, acc1[1][fc], 0, 0, 0);
            bf8v b2 = *(const bf8v*)(bk2 + fc * 512);
            acc2[0][fc] = __builtin_amdgcn_mfma_f32_16x16x32_bf16(a0, b2, acc2[0][fc], 0, 0, 0);
            acc2[1][fc] = __builtin_amdgcn_mfma_f32_16x16x32_bf16(a1, b2, acc2[1][fc], 0, 0, 0);
        }
    }
    // epilogue
    int erow = blockIdx.x * 64 + wr + g * 4;
    int ecol = wc + r15;
    float am[2][4], at[2][4];
#pragma unroll
    for (int fr = 0; fr < 2; ++fr)
#pragma unroll
        for (int r = 0; r < 4; ++r) {
            int row = erow + fr * 16 + r;
            am[fr][r] = amp[row];
            at[fr][r] = att[row];
        }
#pragma unroll
    for (int fc = 0; fc < 4; ++fc) {
        int col = ecol + fc * 16;
        float bv = (col < F_) ? bias[col] : 0.f;
#pragma unroll
        for (int fr = 0; fr < 2; ++fr) {
#pragma unroll
            for (int r = 0; r < 4; ++r) {
                int row = erow + fr * 16 + r;
                float val = acc0[fr][fc][r] + am[fr][r] * acc1[fr][fc][r]
                          + at[fr][r] * acc2[fr][fc][r] + bv;
                C[(size_t)row * 128 + col] = (col < F_) ? f2b(val) : (u16)0;
            }
        }
    }
}

// ---------------- edge aggregation: aggb[nl][512] bf16 ----------------
__global__ void k_aggregate(const float* __restrict__ Pd, const float* __restrict__ Ps,
                            const float* __restrict__ etab_l,
                            const int* __restrict__ deg, const int* __restrict__ rstart,
                            const int* __restrict__ epack, const float* __restrict__ invc,
                            u16* __restrict__ aggb, int n_base) {
    int nl = blockIdx.x;
    int n  = n_base + nl;
    int f  = threadIdx.x;
    u16* arow = aggb + (size_t)nl * 512;
    if (f < 8) arow[504 + f] = 0;
    if (f >= F_) return;
    int dg = deg[n];
    if (dg == 0) {
        arow[f] = 0; arow[F_ + f] = 0; arow[2 * F_ + f] = 0;
        arow[3 * F_ + f] = f2b(sqrtf(EPSV));
        return;
    }
    int rs = rstart[n];
    float c = Pd[(size_t)nl * 128 + f];
    float sum = 0.f, sumsq = 0.f, vmin = 3.4e38f, vmax = -3.4e38f;
    for (int e = 0; e < dg; ++e) {
        int pk = epack[rs + e];
        int s  = (pk & 0xFFFFF) - n_base;
        int a  = pk >> 20;
        float v = Ps[(size_t)s * 128 + f] + etab_l[a * F_ + f];
        sum += v; sumsq += v * v;
        vmin = fminf(vmin, v); vmax = fmaxf(vmax, v);
    }
    float ic  = invc[n];
    float mv  = sum * ic;
    float var = sumsq * ic - mv * mv;
    arow[f]          = f2b(c + mv);
    arow[F_ + f]     = f2b(c + vmin);
    arow[2 * F_ + f] = f2b(c + vmax);
    arow[3 * F_ + f] = f2b(sqrtf(fmaxf(var, 0.f) + EPSV));
}

// ---------------- BN apply + ReLU, vectorized short8 ----------------
__global__ void k_bn_apply(u16* __restrict__ hb, const float* __restrict__ sums,
                           const float* __restrict__ g, const float* __restrict__ b) {
    int idx = (blockIdx.x * 256 + threadIdx.x) * 8;
    if (idx >= NN * 128) return;
    int f0 = idx & 127;
    U4 u;
    u.v = *(const bf8v*)(hb + idx);
    float v[8];
#pragma unroll
    for (int i = 0; i < 4; ++i) { v[2 * i] = b2f_lo(u.a[i]); v[2 * i + 1] = b2f_hi(u.a[i]); }
    float o[8];
#pragma unroll
    for (int j = 0; j < 8; ++j) {
        int f = f0 + j;
        float r = 0.f;
        if (f < F_) {
            float mu  = sums[f] * (1.f / NN);
            float var = sums[128 + f] * (1.f / NN) - mu * mu;
            r = fmaxf(g[f] * (v[j] - mu) * rsqrtf(var + EPSV) + b[f], 0.f);
        }
        o[j] = r;
    }
    U4 w;
#pragma unroll
    for (int i = 0; i < 4; ++i) w.a[i] = (u32)f2b(o[2 * i]) | ((u32)f2b(o[2 * i + 1]) << 16);
    *(bf8v*)(hb + idx) = w.v;
}

// ---------------- pool (per-graph sum, vectorized) + 4-layer MLP head (fp32) --------------
__global__ __launch_bounds__(256) void k_pool_mlp(const u16* __restrict__ hb,
        const float* __restrict__ w1, const float* __restrict__ b1,
        const float* __restrict__ w2, const float* __restrict__ b2,
        const float* __restrict__ w3, const float* __restrict__ b3,
        const float* __restrict__ w4, const float* __restrict__ b4,
        float* __restrict__ out) {
    int gg = blockIdx.x;
    __shared__ float lsum[16][128];
    __shared__ float p[128];
    __shared__ float z1[100];
    __shared__ float z2[50];
    __shared__ float z3[25];
    int t = threadIdx.x;
    int cg = t & 15, rs = t >> 4;
    const u16* hbase = hb + (size_t)gg * NPG * 128 + cg * 8;
    float a8[8] = {};
    for (int r = rs; r < NPG; r += 16) {
        U4 u;
        u.v = *(const bf8v*)(hbase + (size_t)r * 128);
#pragma unroll
        for (int i = 0; i < 4; ++i) { a8[2 * i] += b2f_lo(u.a[i]); a8[2 * i + 1] += b2f_hi(u.a[i]); }
    }
#pragma unroll
    for (int j = 0; j < 8; ++j) lsum[rs][cg * 8 + j] = a8[j];
    __syncthreads();
    if (t < 128) {
        float s = 0.f;
#pragma unroll
        for (int k = 0; k < 16; ++k) s += lsum[k][t];
        p[t] = s;
    }
    __syncthreads();
    if (t < 100) {
        float s = b1[t];
        for (int c = 0; c < F_; ++c) s += p[c] * w1[c * 100 + t];
        z1[t] = fmaxf(s, 0.f);
    }
    __syncthreads();
    if (t < 50) {
        float s = b2[t];
        for (int c = 0; c < 100; ++c) s += z1[c] * w2[c * 50 + t];
        z2[t] = fmaxf(s, 0.f);
    }
    __syncthreads();
    if (t < 25) {
        float s = b3[t];
        for (int c = 0; c < 50; ++c) s += z2[c] * w3[c * 25 + t];
        z3[t] = fmaxf(s, 0.f);
    }
    __syncthreads();
    if (t == 0) {
        float s = b4[0];
        for (int c = 0; c < 25; ++c) s += z3[c] * w4[c];
        out[gg] = s;
    }
}

extern "C" void kernel_launch(void* const* d_in, const int* in_sizes, int n_in,
                              void* d_out, int out_size, void* d_ws, size_t ws_size,
                              hipStream_t stream) {
    const float* x        = (const float*)d_in[0];
    const int*   ei       = (const int*)d_in[1];
    const int*   src      = ei;
    const int*   dst      = ei + EE;
    const int*   eattr    = (const int*)d_in[2];
    const int*   deg_hist = (const int*)d_in[4];
    const float* emb1_w = (const float*)d_in[5];
    const float* emb1_b = (const float*)d_in[6];
    const float* edge_tab = (const float*)d_in[7];
    const float* enc_w  = (const float*)d_in[8];
    const float* enc_b  = (const float*)d_in[9];
    const float* pre_w  = (const float*)d_in[10];
    const float* pre_b  = (const float*)d_in[11];
    const float* post_w = (const float*)d_in[12];
    const float* post_b = (const float*)d_in[13];
    const float* lin_w  = (const float*)d_in[14];
    const float* lin_b  = (const float*)d_in[15];
    const float* bn_g   = (const float*)d_in[16];
    const float* bn_b   = (const float*)d_in[17];
    const float* w1 = (const float*)d_in[18];
    const float* b1 = (const float*)d_in[19];
    const float* w2 = (const float*)d_in[20];
    const float* b2 = (const float*)d_in[21];
    const float* w3 = (const float*)d_in[22];
    const float* b3 = (const float*)d_in[23];
    const float* w4 = (const float*)d_in[24];
    const float* b4 = (const float*)d_in[25];
    float* out = (float*)d_out;

    // ---- workspace layout (~114 MiB) ----
    char* base = (char*)d_ws;
    size_t o = 0;
    auto alloc = [&](size_t bytes) { char* r = base + o; o = (o + bytes + 255) & ~(size_t)255; return r; };
    u16*  hb    = (u16*)  alloc((size_t)NN * 128 * 2);
    float* Pd   = (float*)alloc((size_t)CH * 128 * 4);
    float* Ps   = (float*)alloc((size_t)CH * 128 * 4);
    u16*  aggb  = (u16*)  alloc((size_t)CH * 512 * 2);
    u16*  outA  = (u16*)  alloc((size_t)CH * 128 * 2);
    float* etab = (float*)alloc(4 * 10 * F_ * 4);
    float* invc = (float*)alloc((size_t)NN * 4);
    float* ampv = (float*)alloc((size_t)NN * 4);
    float* attv = (float*)alloc((size_t)NN * 4);
    float* bnsums = (float*)alloc(1024);
    int*  deg    = (int*)alloc((size_t)NN * 4);
    int*  rstart = (int*)alloc((size_t)NN * 4);
    int*  epack  = (int*)alloc((size_t)EE * 4);
    u16*  wiB   = (u16*)alloc((size_t)4 * SMALLB_SZ * 2);
    u16*  wjB   = (u16*)alloc((size_t)4 * SMALLB_SZ * 2);
    u16*  linB  = (u16*)alloc((size_t)4 * SMALLB_SZ * 2);
    u16*  postB = (u16*)alloc((size_t)4 * POSTB_SZ * 2);

    // ---- setup ----
    k_embed<<<(NN * 128 / 8 + 255) / 256, 256, 0, stream>>>(x, emb1_w, emb1_b, hb);
    k_build_csr<<<G_, 128, 0, stream>>>(src, dst, eattr, deg, rstart, epack);
    k_node_scalars<<<(NN + 255) / 256, 256, 0, stream>>>(deg, deg_hist, invc, ampv, attv);
    k_build_etab<<<40, 128, 0, stream>>>(edge_tab, enc_w, enc_b, pre_w, pre_b, etab);
    k_prep_B128<<<dim3(SMALLB_SZ / 256, 12), 256, 0, stream>>>(pre_w, lin_w, wiB, wjB, linB);
    k_prep_Bpost<<<dim3((POSTB_SZ + 255) / 256, 4), 256, 0, stream>>>(post_w, postB);

    for (int l = 0; l < 4; ++l) {
        hipMemsetAsync(bnsums, 0, 1024, stream);
        for (int c = 0; c < NCHUNK; ++c) {
            u16* hc = hb + (size_t)c * CH * 128;
            int  nb = c * CH;
            // Pd = hc@Wi, Ps = hc@Wj (fp32 out, one dual launch)
            k_gemm_mfma<1, 0><<<dim3(CH / 64, 2), 256, 0, stream>>>(
                hc, wiB + (size_t)l * SMALLB_SZ, wjB + (size_t)l * SMALLB_SZ,
                nullptr, nullptr, Pd, Ps, nullptr);
            k_aggregate<<<CH, 128, 0, stream>>>(Pd, Ps, etab + l * 10 * F_, deg, rstart,
                                                epack, invc, aggb, nb);
            // outA = h@B0 + agg@B1 + amp*(agg@B2) + att*(agg@B3) + post_b
            k_gemm_post<<<dim3(CH / 64, 1), 256, 0, stream>>>(
                hc, aggb, ampv + nb, attv + nb,
                postB + (size_t)l * POSTB_SZ, post_b + l * F_, outA);
            // hc = outA @ lin_w + lin_b (bf16, in place) + fused BN stats
            k_gemm_mfma<0, 1><<<dim3(CH / 64, 1), 256, 0, stream>>>(
                outA, linB + (size_t)l * SMALLB_SZ, linB + (size_t)l * SMALLB_SZ,
                lin_b + l * F_, lin_b + l * F_, hc, hc, bnsums);
        }
        // BatchNorm apply + ReLU in place on hb (vectorized)
        k_bn_apply<<<(NN * 128 / 8 + 255) / 256, 256, 0, stream>>>(hb, bnsums,
                                                                   bn_g + l * F_, bn_b + l * F_);
    }

    k_pool_mlp<<<G_, 256, 0, stream>>>(hb, w1, b1, w2, b2, w3, b3, w4, b4, out);
}